// Round 9
// baseline (25.318 us; speedup 1.0000x reference)
//
#include <hip/hip_runtime.h>

#define HH 512
#define WW 512
#define HWPIX (HH * WW)
#define BPB 64            // blocks per batch
#define NB  32            // batches
#define NT  256

typedef unsigned long long u64;
typedef unsigned u32;

#define SLOT_WORDS 3
#define TAG     ((u64)1 << 62)          // bits 63:62 = '01'
#define TAGMASK ((u64)3 << 62)          // poison 0xAA.. = '10', zeros = '00'

__device__ __forceinline__ u32 f2u(float f) { union { float f; u32 u; } c; c.f = f; return c.u; }
__device__ __forceinline__ float u2f(u32 u) { union { float f; u32 u; } c; c.u = u; return c.f; }

// ws layout: u64 slots[NB][BPB][3]  (48 KB)  |  u32 counters[NB][16] (64B stride, 2 KB)
__global__ __launch_bounds__(NT)
void mfe_fused(const float* __restrict__ in, u64* __restrict__ slots,
               u32* __restrict__ counters, float* __restrict__ out) {
    const int b = blockIdx.y, k = blockIdx.x, tid = threadIdx.x;

    const float4* p0 = (const float4*)(in + (size_t)b * 3 * HWPIX);
    const float4* p1 = p0 + (HWPIX / 4);
    const float4* p2 = p0 + (HWPIX / 2);

    int   cnt = 0;                 // pa | va<<16 (block totals <= 4096)
    float pc = 0.f, vc = 0.f;
    int   rmin = HH, rmax = -1, cmin = WW, cmax = -1;

    // consecutive lanes -> consecutive float4 (1KB per load instr, coalesced)
    for (int g = k * NT + tid; g < HWPIX / 4; g += BPB * NT) {
        float4 a  = p0[g];
        float4 b4 = p1[g];
        float4 c4 = p2[g];
        const int row     = g >> 7;          // 128 float4 per 512-px row
        const int colbase = (g & 127) << 2;
        unsigned msk = 0u;
        const float* A = (const float*)&a;
        const float* B = (const float*)&b4;
        const float* C = (const float*)&c4;
        #pragma unroll
        for (int j = 0; j < 4; ++j) {
            float l0 = A[j], l1 = B[j], l2 = C[j];
            float m01 = fmaxf(l0, l1);
            float m   = fmaxf(m01, l2);
            float t0 = l0 - m, t1 = l1 - m, t2 = l2 - m;   // t_max == 0
            float tmin = fminf(fminf(t0, t1), t2);
            float tmid = ((t0 + t1) + t2) - tmin;           // mid = sum - min
            float s    = 1.0f + __expf(tmid) + __expf(tmin);
            float conf = __builtin_amdgcn_rcpf(s);          // softmax prob of argmax
            bool isV = l2 > m01;                            // pred==2 (first-index)
            bool isP = (l1 > l0) && !isV;                   // pred==1
            cnt += (int)isP | ((int)isV << 16);
            pc  += isP ? conf : 0.f;
            vc  += isV ? conf : 0.f;
            msk |= (unsigned)isP << j;
        }
        if (msk) {
            rmin = min(rmin, row);
            rmax = max(rmax, row);
            cmin = min(cmin, colbase + (__ffs(msk) - 1));
            cmax = max(cmax, colbase + (31 - __clz(msk)));
        }
    }

    // wave (64-lane) shuffle reduce
    #pragma unroll
    for (int off = 32; off > 0; off >>= 1) {
        cnt += __shfl_down(cnt, off, 64);
        pc  += __shfl_down(pc, off, 64);
        vc  += __shfl_down(vc, off, 64);
        rmin = min(rmin, __shfl_down(rmin, off, 64));
        rmax = max(rmax, __shfl_down(rmax, off, 64));
        cmin = min(cmin, __shfl_down(cmin, off, 64));
        cmax = max(cmax, __shfl_down(cmax, off, 64));
    }

    struct SPart { int cnt; float pc, vc; int rmin, rmax, cmin, cmax; };
    __shared__ SPart sp[NT / 64];
    __shared__ u64 sw[SLOT_WORDS][BPB];
    __shared__ int lastFlag;
    const int lane = tid & 63, wid = tid >> 6;
    if (lane == 0) sp[wid] = SPart{cnt, pc, vc, rmin, rmax, cmin, cmax};
    __syncthreads();

    if (tid == 0) {
        SPart r = sp[0];
        #pragma unroll
        for (int w = 1; w < NT / 64; ++w) {
            r.cnt += sp[w].cnt;
            r.pc  += sp[w].pc;   r.vc += sp[w].vc;
            r.rmin = min(r.rmin, sp[w].rmin);
            r.rmax = max(r.rmax, sp[w].rmax);
            r.cmin = min(r.cmin, sp[w].cmin);
            r.cmax = max(r.cmax, sp[w].cmax);
        }
        const u32 pa = (u32)(r.cnt & 0xFFFF), va = (u32)(r.cnt >> 16);
        // Pack partial into 3 tagged words; publish with relaxed agent-scope
        // atomic stores (coherence-point visible, NO fence / L2 flush).
        u64 w0 = TAG | ((u64)pa << 33) | ((u64)va << 20)
                     | ((u64)(u32)r.rmin << 10) | (u64)(u32)(r.rmax + 1);
        u64 w1 = TAG | ((u64)(u32)r.cmin << 42) | ((u64)(u32)(r.cmax + 1) << 32)
                     | (u64)f2u(r.pc);
        u64 w2 = TAG | (u64)f2u(r.vc);
        u64* slot = slots + ((size_t)b * BPB + k) * SLOT_WORDS;
        __hip_atomic_store(&slot[0], w0, __ATOMIC_RELAXED, __HIP_MEMORY_SCOPE_AGENT);
        __hip_atomic_store(&slot[1], w1, __ATOMIC_RELAXED, __HIP_MEMORY_SCOPE_AGENT);
        __hip_atomic_store(&slot[2], w2, __ATOMIC_RELAXED, __HIP_MEMORY_SCOPE_AGENT);
        // Arrival. atomicInc wrap-at-63 makes "64th arriver" robust to ANY
        // initial counter value (poison/zero/garbage): exactly one finalizer.
        u32 old = atomicInc(&counters[b * 16], 63u);
        lastFlag = (old == 62u);   // see analysis: fires exactly once per call
    }
    __syncthreads();
    if (!lastFlag) return;

    // ---- finalizer block for batch b: poll tags, reduce, featurize ----
    if (tid < 64 * SLOT_WORDS) {
        const int w = tid >> 6, s = tid & 63;
        u64* p = slots + ((size_t)b * BPB + s) * SLOT_WORDS + w;
        u64 v;
        do {
            v = __hip_atomic_load(p, __ATOMIC_RELAXED, __HIP_MEMORY_SCOPE_AGENT);
        } while ((v & TAGMASK) != TAG);
        sw[w][s] = v;
    }
    __syncthreads();

    if (tid < 64) {
        const u64 v0 = sw[0][tid], v1 = sw[1][tid], v2 = sw[2][tid];
        int pa2 = (int)((v0 >> 33) & 0x1FFF);
        int va2 = (int)((v0 >> 20) & 0x1FFF);
        int rmin2 = (int)((v0 >> 10) & 0x3FF);
        int rmax2 = (int)(v0 & 0x3FF) - 1;
        int cmin2 = (int)((v1 >> 42) & 0x3FF);
        int cmax2 = (int)((v1 >> 32) & 0x3FF) - 1;
        float pc2 = u2f((u32)v1);
        float vc2 = u2f((u32)v2);

        #pragma unroll
        for (int off = 32; off > 0; off >>= 1) {
            pa2 += __shfl_down(pa2, off, 64);
            va2 += __shfl_down(va2, off, 64);
            pc2 += __shfl_down(pc2, off, 64);
            vc2 += __shfl_down(vc2, off, 64);
            rmin2 = min(rmin2, __shfl_down(rmin2, off, 64));
            rmax2 = max(rmax2, __shfl_down(rmax2, off, 64));
            cmin2 = min(cmin2, __shfl_down(cmin2, off, 64));
            cmax2 = max(cmax2, __shfl_down(cmax2, off, 64));
        }
        if (tid == 0) {
            const float paf = (float)pa2;
            const float vaf = (float)va2;
            const float fa  = paf + vaf;                  // fg = plaque + vessel
            const bool  ne  = (rmax2 >= 0);
            const float hr  = ne ? (float)(rmax2 - rmin2) : 0.f;
            const float wr  = ne ? (float)(cmax2 - cmin2) : 0.f;
            float* o = out + b * 10;
            o[0] = paf / (vaf + 1e-6f);
            o[1] = paf / (fa + 1e-6f);
            o[2] = pc2;
            o[3] = hr / (float)HH;
            o[4] = wr / (float)WW;
            o[5] = 2.0f * (hr + wr) / (float)(HH + WW);
            o[6] = vc2;
            o[7] = (pa2 > 0) ? (pc2 / (paf + 1e-6f)) : 0.f;
            o[8] = fa / (float)HWPIX;
            o[9] = paf / (float)HWPIX;
        }
    }
}

extern "C" void kernel_launch(void* const* d_in, const int* in_sizes, int n_in,
                              void* d_out, int out_size, void* d_ws, size_t ws_size,
                              hipStream_t stream) {
    const float* in  = (const float*)d_in[0];
    float*       out = (float*)d_out;
    u64*         slots = (u64*)d_ws;
    u32*         counters = (u32*)((char*)d_ws + (size_t)NB * BPB * SLOT_WORDS * 8);

    dim3 grid(BPB, NB);
    mfe_fused<<<grid, NT, 0, stream>>>(in, slots, counters, out);
}

// Round 10
// 25.149 us; speedup vs baseline: 1.0067x; 1.0067x over previous
//
#include <hip/hip_runtime.h>

#define HH 512
#define WW 512
#define HWPIX (HH * WW)
#define BPB 64            // blocks per batch
#define NB  32            // batches
#define NT  256

typedef unsigned long long u64;

struct Partial {
    int   pa, va;          // plaque / vessel counts
    float pc, vc;          // conf-weighted sums
    int   rmin, rmax, cmin, cmax;  // plaque bbox
};

__global__ __launch_bounds__(NT)
void mfe_reduce(const float* __restrict__ in, Partial* __restrict__ part) {
    const int b = blockIdx.y, k = blockIdx.x, tid = threadIdx.x;
    const int lane = tid & 63, wid = tid >> 6;

    const float4* p0 = (const float4*)(in + (size_t)b * 3 * HWPIX);
    const float4* p1 = p0 + (HWPIX / 4);
    const float4* p2 = p0 + (HWPIX / 2);

    float pc = 0.f, vc = 0.f;
    int   spa = 0, sva = 0;              // wave-scalar counts (SALU)
    int   rmin = HH, rmax = -1, cmin = WW, cmax = -1;  // wave-scalar bbox

    #pragma unroll
    for (int i = 0; i < 4; ++i) {
        const int g = k * NT + i * (BPB * NT) + tid;   // consecutive lanes ->
        float4 a  = p0[g];                             // consecutive float4
        float4 b4 = p1[g];
        float4 c4 = p2[g];
        // Wave-uniform geometry: g-lane is 64-aligned; 128 float4 per row and
        // 64-aligned start => no row wrap within a wave. row uniform, col
        // monotonic in lane. Force into SGPRs.
        const int gw   = __builtin_amdgcn_readfirstlane(g - lane);
        const int row  = gw >> 7;
        const int colb = (gw & 127) << 2;              // col of lane 0 at j=0
        const float* A = (const float*)&a;
        const float* B = (const float*)&b4;
        const float* C = (const float*)&c4;
        #pragma unroll
        for (int j = 0; j < 4; ++j) {
            float l0 = A[j], l1 = B[j], l2 = C[j];
            float m01 = fmaxf(l0, l1);
            float m   = fmaxf(m01, l2);
            float t0 = l0 - m, t1 = l1 - m, t2 = l2 - m;   // t_max == 0
            float tmin = fminf(fminf(t0, t1), t2);
            float tmid = ((t0 + t1) + t2) - tmin;           // mid = sum - min
            float s    = 1.0f + __expf(tmid) + __expf(tmin);
            float conf = __builtin_amdgcn_rcpf(s);          // softmax p of argmax
            bool isV = l2 > m01;                            // pred==2 (first-idx)
            bool isP = (l1 > l0) && !isV;                   // pred==1
            u64 mV = __ballot(isV);
            u64 mP = __ballot(isP);
            spa += __popcll(mP);                            // scalar count
            sva += __popcll(mV);
            pc  += isP ? conf : 0.f;                        // per-lane fp sums
            vc  += isV ? conf : 0.f;
            if (mP) {                                       // wave-uniform branch
                rmin = min(rmin, row);
                rmax = max(rmax, row);
                int lo = __ffsll(mP) - 1;                   // lowest  lane set
                int hi = 63 - __builtin_clzll(mP);          // highest lane set
                cmin = min(cmin, colb + (lo << 2) + j);
                cmax = max(cmax, colb + (hi << 2) + j);
            }
        }
    }

    // Only pc/vc need a cross-lane reduce (counts+bbox already wave-scalar).
    #pragma unroll
    for (int off = 32; off > 0; off >>= 1) {
        pc += __shfl_down(pc, off, 64);
        vc += __shfl_down(vc, off, 64);
    }

    __shared__ Partial sp[NT / 64];
    if (lane == 0) sp[wid] = Partial{spa, sva, pc, vc, rmin, rmax, cmin, cmax};
    __syncthreads();
    if (tid == 0) {
        Partial r = sp[0];
        #pragma unroll
        for (int w = 1; w < NT / 64; ++w) {
            r.pa += sp[w].pa;  r.va += sp[w].va;
            r.pc += sp[w].pc;  r.vc += sp[w].vc;
            r.rmin = min(r.rmin, sp[w].rmin);
            r.rmax = max(r.rmax, sp[w].rmax);
            r.cmin = min(r.cmin, sp[w].cmin);
            r.cmax = max(r.cmax, sp[w].cmax);
        }
        part[b * BPB + k] = r;
    }
}

__global__ __launch_bounds__(64)
void mfe_finalize(const Partial* __restrict__ part, float* __restrict__ out) {
    const int b    = blockIdx.x;
    const int lane = threadIdx.x;
    Partial r = part[b * BPB + lane];
    int pa = r.pa, va = r.va;
    float pc = r.pc, vc = r.vc;
    int rmin = r.rmin, rmax = r.rmax, cmin = r.cmin, cmax = r.cmax;

    #pragma unroll
    for (int off = 32; off > 0; off >>= 1) {
        pa += __shfl_down(pa, off, 64);
        va += __shfl_down(va, off, 64);
        pc += __shfl_down(pc, off, 64);
        vc += __shfl_down(vc, off, 64);
        rmin = min(rmin, __shfl_down(rmin, off, 64));
        rmax = max(rmax, __shfl_down(rmax, off, 64));
        cmin = min(cmin, __shfl_down(cmin, off, 64));
        cmax = max(cmax, __shfl_down(cmax, off, 64));
    }

    if (lane == 0) {
        const float paf = (float)pa;
        const float vaf = (float)va;
        const float fa  = paf + vaf;                  // fg = plaque + vessel
        const bool  ne  = (rmax >= 0);
        const float hr  = ne ? (float)(rmax - rmin) : 0.f;
        const float wr  = ne ? (float)(cmax - cmin) : 0.f;
        float* o = out + b * 10;
        o[0] = paf / (vaf + 1e-6f);
        o[1] = paf / (fa + 1e-6f);
        o[2] = pc;
        o[3] = hr / (float)HH;
        o[4] = wr / (float)WW;
        o[5] = 2.0f * (hr + wr) / (float)(HH + WW);
        o[6] = vc;
        o[7] = (pa > 0) ? (pc / (paf + 1e-6f)) : 0.f;
        o[8] = fa / (float)HWPIX;
        o[9] = paf / (float)HWPIX;
    }
}

extern "C" void kernel_launch(void* const* d_in, const int* in_sizes, int n_in,
                              void* d_out, int out_size, void* d_ws, size_t ws_size,
                              hipStream_t stream) {
    const float* in  = (const float*)d_in[0];
    float*       out = (float*)d_out;
    Partial*     part = (Partial*)d_ws;

    dim3 grid(BPB, NB);
    mfe_reduce<<<grid, NT, 0, stream>>>(in, part);
    mfe_finalize<<<NB, 64, 0, stream>>>(part, out);
}